// Round 5
// baseline (677.207 us; speedup 1.0000x reference)
//
#include <hip/hip_runtime.h>
#include <math.h>

// Problem constants (from reference): B=2, A=1152, DET=736, N=512.
// ws layout (floats):
//   [0, 736)                      : h filter taps (|d| <= 735)
//   [736 + b*3056 + 0, +2304)     : per-batch sin/cos table (interleaved, 1152 angles)
//   [736 + b*3056 + 2304, +736)   : per-batch detector weight w[j] = vox*cosw[j]/du_v
//   [736 + b*3056 + 3040, +16)    : per-batch scalars {dso_s, k1=dso_s/du_v, center, A, B}
//   [736 + B*3056, ...)           : filtered sinogram [B][A][DET]
#define PB_SIZE 3056
#define SC_LEN  2304
#define W_OFF   2304
#define S_OFF   3040

__global__ void prep_kernel(const float* __restrict__ angles,
                            const float* __restrict__ dso,
                            const float* __restrict__ ddo,
                            const float* __restrict__ du,
                            const float* __restrict__ hu,
                            float* __restrict__ ws, int nang, int ndet)
{
    int b = blockIdx.x;
    int t = threadIdx.x;
    const float vox = 1.0f / 0.7f;
    float dsov = dso[b];
    float dso_s = vox * dsov;
    float sd_s  = vox * (dsov + ddo[b]);
    float du_s  = vox * du[b];
    float du_v  = du_s * dso_s / sd_s;
    float beta0 = angles[(size_t)b * nang];
    float dbeta = angles[(size_t)b * nang + 1] - beta0;  // A_hr*inc/A_sr with A_hr==A_sr
    float center = 0.5f * (float)(ndet - 1);

    // Ramp-filter spatial taps (both batch-blocks write identical values; benign)
    for (int d = t; d < ndet; d += blockDim.x) {
        float v = 0.0f;
        if (d == 0) v = 0.5f;
        else if (d & 1) {
            float pd = 3.14159265358979323846f * (float)d;
            v = -2.0f / (pd * pd);
        }
        ws[d] = v;
    }

    float* pb = ws + 736 + b * PB_SIZE;
    for (int i = t; i < nang; i += blockDim.x) {
        float beta = beta0 + dbeta * (float)i;
        pb[2 * i]     = sinf(beta);
        pb[2 * i + 1] = cosf(beta);
    }
    float* w = pb + W_OFF;
    for (int j = t; j < ndet; j += blockDim.x) {
        float uk = ((float)j - center) * du_v;
        float cosw = dso_s / sqrtf(dso_s * dso_s + uk * uk);
        w[j] = vox * cosw / du_v;
    }
    if (t == 0) {
        float hu0 = fabsf(hu[b]);
        if (hu0 < 1e-6f) hu0 = 1e-6f;
        float* s = pb + S_OFF;
        s[0] = dso_s;
        s[1] = dso_s / du_v;
        s[2] = center;
        s[3] = 1000.0f * 0.5f * dbeta / (hu0 + 1e-6f);
        s[4] = -1000.0f * hu0 / (hu0 + 1e-6f);
    }
}

// One block per (angle, batch) row: weighted row staged in LDS (zero-padded both
// sides), then direct symmetric convolution with the odd-tap ramp kernel.
__global__ __launch_bounds__(256) void filter_kernel(const float* __restrict__ sino,
                                                     const float* __restrict__ ws,
                                                     float* __restrict__ filtered,
                                                     int nang, int ndet)
{
    __shared__ float row[3 * 736];  // [0,736) pad | [736,1472) data | [1472,2208) pad
    __shared__ float hl[736];
    int a = blockIdx.x;
    int b = blockIdx.y;
    int t = threadIdx.x;
    const float* srow = sino + ((size_t)b * nang + a) * (size_t)ndet;
    const float* wtab = ws + 736 + b * PB_SIZE + W_OFF;

    for (int i = t; i < 736; i += 256) {
        row[i] = 0.0f;
        row[1472 + i] = 0.0f;
    }
    for (int j = t; j < ndet; j += 256)
        row[736 + j] = srow[j] * wtab[j];
    for (int d = t; d < 736; d += 256)
        hl[d] = ws[d];
    __syncthreads();

    float* frow = filtered + ((size_t)b * nang + a) * (size_t)ndet;
    for (int i = t; i < ndet; i += 256) {
        const float* rp = row + 736 + i;
        float acc = 0.5f * rp[0];
        #pragma unroll 4
        for (int d = 1; d < 736; d += 2) {
            acc += hl[d] * (rp[-d] + rp[d]);
        }
        frow[i] = acc;
    }
}

// 16x16 pixel tile per block; loop over all angles; per-angle sin/cos from LDS
// (wave-uniform broadcast); bilinear gather from L2-resident filtered sinogram.
__global__ __launch_bounds__(256) void backproject_kernel(const float* __restrict__ ws,
                                                          const float* __restrict__ filtered,
                                                          float* __restrict__ out,
                                                          int nang, int ndet)
{
    __shared__ float sc[2 * 1152];
    int b = blockIdx.z;
    const float* pb = ws + 736 + b * PB_SIZE;
    const float* sp = pb + S_OFF;
    float dso_s = sp[0];
    float k1    = sp[1];
    float center= sp[2];
    float As    = sp[3];
    float Bs    = sp[4];

    int tid = threadIdx.y * 16 + threadIdx.x;
    for (int i = tid; i < 2 * nang; i += 256)
        sc[i] = pb[i];
    __syncthreads();

    int cx = blockIdx.x * 16 + threadIdx.x;
    int cy = blockIdx.y * 16 + threadIdx.y;
    float X = (float)cx - 255.5f;
    float Y = (float)cy - 255.5f;
    const float* fb = filtered + (size_t)b * nang * ndet;
    float acc = 0.0f;
    float detm1 = (float)(ndet - 1);

    for (int a = 0; a < nang; ++a) {
        float s = sc[2 * a];
        float c = sc[2 * a + 1];
        float U = dso_s + X * s - Y * c;            // always > 0 for this geometry
        float r = __builtin_amdgcn_rcpf(U);         // v_rcp_f32, ~1ulp — ample precision
        float t = X * c + Y * s;
        float u = k1 * t * r + center;
        float fi = floorf(u);
        float w = u - fi;
        int i0 = (int)fi;
        int i0c = min(max(i0, 0), ndet - 1);
        int i1c = min(max(i0 + 1, 0), ndet - 1);
        const float* frow = fb + (size_t)a * ndet;
        float q0 = frow[i0c];
        float q1 = frow[i1c];
        float d = dso_s * r;
        float wt = d * d;
        bool valid = (u >= 0.0f) && (u <= detm1);
        float val = q0 + (q1 - q0) * w;
        acc += valid ? val * wt : 0.0f;
    }
    out[((size_t)b * 512 + cy) * 512 + cx] = As * acc + Bs;
}

extern "C" void kernel_launch(void* const* d_in, const int* in_sizes, int n_in,
                              void* d_out, int out_size, void* d_ws, size_t ws_size,
                              hipStream_t stream)
{
    const float* sino   = (const float*)d_in[0];
    const float* angles = (const float*)d_in[1];
    const float* dso    = (const float*)d_in[2];
    const float* ddo    = (const float*)d_in[3];
    const float* du     = (const float*)d_in[4];
    const float* hu     = (const float*)d_in[5];
    float* ws  = (float*)d_ws;
    float* out = (float*)d_out;

    int B    = in_sizes[2];
    int nang = in_sizes[1] / B;
    int ndet = in_sizes[0] / (B * nang);

    float* filtered = ws + 736 + B * PB_SIZE;

    prep_kernel<<<B, 256, 0, stream>>>(angles, dso, ddo, du, hu, ws, nang, ndet);
    filter_kernel<<<dim3(nang, B), 256, 0, stream>>>(sino, ws, filtered, nang, ndet);
    backproject_kernel<<<dim3(512 / 16, 512 / 16, B), dim3(16, 16), 0, stream>>>(
        ws, filtered, out, nang, ndet);
}

// Round 6
// 498.250 us; speedup vs baseline: 1.3592x; 1.3592x over previous
//
#include <hip/hip_runtime.h>
#include <math.h>

// Problem constants (from reference): B=2, A=1152, DET=736, N=512.
// ws layout (floats):
//   [0, 736)                      : h filter taps (|d| <= 735)
//   [736 + b*3056 + 0, +2304)     : per-batch sin/cos table (interleaved, 1152 angles)
//   [736 + b*3056 + 2304, +736)   : per-batch detector weight w[j] = vox*cosw[j]/du_v
//   [736 + b*3056 + 3040, +16)    : per-batch scalars {dso_s, k1, center, A, B, geom_same}
//   [736 + B*3056, ...)           : filtered sinogram [B][A][DET]
#define PB_SIZE 3056
#define W_OFF   2304
#define S_OFF   3040

__global__ void prep_kernel(const float* __restrict__ angles,
                            const float* __restrict__ dso,
                            const float* __restrict__ ddo,
                            const float* __restrict__ du,
                            const float* __restrict__ hu,
                            float* __restrict__ ws, int nang, int ndet, int B)
{
    int b = blockIdx.x;
    int t = threadIdx.x;
    const float vox = 1.0f / 0.7f;
    float dsov = dso[b];
    float dso_s = vox * dsov;
    float sd_s  = vox * (dsov + ddo[b]);
    float du_s  = vox * du[b];
    float du_v  = du_s * dso_s / sd_s;
    float beta0 = angles[(size_t)b * nang];
    float dbeta = angles[(size_t)b * nang + 1] - beta0;  // A_hr*inc/A_sr with A_hr==A_sr
    float center = 0.5f * (float)(ndet - 1);

    // Ramp-filter spatial taps (both batch-blocks write identical values; benign)
    for (int d = t; d < ndet; d += blockDim.x) {
        float v = 0.0f;
        if (d == 0) v = 0.5f;
        else if (d & 1) {
            float pd = 3.14159265358979323846f * (float)d;
            v = -2.0f / (pd * pd);
        }
        ws[d] = v;
    }

    float* pb = ws + 736 + b * PB_SIZE;
    for (int i = t; i < nang; i += blockDim.x) {
        float beta = beta0 + dbeta * (float)i;
        pb[2 * i]     = sinf(beta);
        pb[2 * i + 1] = cosf(beta);
    }
    float* w = pb + W_OFF;
    for (int j = t; j < ndet; j += blockDim.x) {
        float uk = ((float)j - center) * du_v;
        float cosw = dso_s / sqrtf(dso_s * dso_s + uk * uk);
        w[j] = vox * cosw / du_v;
    }
    if (t == 0) {
        float hu0 = fabsf(hu[b]);
        if (hu0 < 1e-6f) hu0 = 1e-6f;
        float* s = pb + S_OFF;
        s[0] = dso_s;
        s[1] = dso_s / du_v;
        s[2] = center;
        s[3] = 1000.0f * 0.5f * dbeta / (hu0 + 1e-6f);
        s[4] = -1000.0f * hu0 / (hu0 + 1e-6f);
        if (b == 0) {
            // geometry-equality flag: if true, backprojection indices/weights are
            // identical across both batches and can be computed once.
            int same = 0;
            if (B == 2) {
                same = (dso[0] == dso[1]) && (ddo[0] == ddo[1]) && (du[0] == du[1]) &&
                       (angles[0] == angles[nang]) && (angles[1] == angles[nang + 1]);
            }
            s[5] = (float)same;
        }
    }
}

// One block per (angle, batch) row: weighted row staged in LDS (zero-padded both
// sides), then direct symmetric convolution with the odd-tap ramp kernel.
__global__ __launch_bounds__(256) void filter_kernel(const float* __restrict__ sino,
                                                     const float* __restrict__ ws,
                                                     float* __restrict__ filtered,
                                                     int nang, int ndet)
{
    __shared__ float row[3 * 736];  // [0,736) pad | [736,1472) data | [1472,2208) pad
    __shared__ float hl[736];
    int a = blockIdx.x;
    int b = blockIdx.y;
    int t = threadIdx.x;
    const float* srow = sino + ((size_t)b * nang + a) * (size_t)ndet;
    const float* wtab = ws + 736 + b * PB_SIZE + W_OFF;

    for (int i = t; i < 736; i += 256) {
        row[i] = 0.0f;
        row[1472 + i] = 0.0f;
    }
    for (int j = t; j < ndet; j += 256)
        row[736 + j] = srow[j] * wtab[j];
    for (int d = t; d < 736; d += 256)
        hl[d] = ws[d];
    __syncthreads();

    float* frow = filtered + ((size_t)b * nang + a) * (size_t)ndet;
    for (int i = t; i < ndet; i += 256) {
        const float* rp = row + 736 + i;
        float acc = 0.5f * rp[0];
        #pragma unroll 4
        for (int d = 1; d < 736; d += 2) {
            acc += hl[d] * (rp[-d] + rp[d]);
        }
        frow[i] = acc;
    }
}

// 16x16 pixel tile per block. Fused path (geom_same): one geometry evaluation
// per angle feeds bilinear gathers from BOTH batches (same 32-bit row offset,
// two SGPR bases). Generic fallback: per-batch loop with original math.
__global__ __launch_bounds__(256) void backproject_fused(const float* __restrict__ ws,
                                                         const float* __restrict__ filtered,
                                                         float* __restrict__ out,
                                                         int nang, int ndet, int B)
{
    __shared__ float sc[2 * 1152];
    int tid = threadIdx.y * 16 + threadIdx.x;
    int cx = blockIdx.x * 16 + threadIdx.x;
    int cy = blockIdx.y * 16 + threadIdx.y;
    float X = (float)cx - 255.5f;
    float Y = (float)cy - 255.5f;

    const float* pb0 = ws + 736;
    const float* sp0 = pb0 + S_OFF;
    int fused = (sp0[5] != 0.0f);

    if (fused) {
        for (int i = tid; i < 2 * nang; i += 256)
            sc[i] = pb0[i];
        __syncthreads();
        float dso_s = sp0[0];
        float k1    = sp0[1];
        float hc    = sp0[2];            // center == (ndet-1)/2 == half valid range
        const float* sp1 = sp0 + PB_SIZE;
        float Xk = X * k1;
        float Yk = Y * k1;
        const float* fb0 = filtered;
        const float* fb1 = filtered + (size_t)nang * ndet;
        float acc0 = 0.0f, acc1 = 0.0f;
        int rowoff = 0;
        for (int a = 0; a < nang; ++a, rowoff += ndet) {
            float s = sc[2 * a];
            float c = sc[2 * a + 1];
            float U = fmaf(X, s, dso_s) - Y * c;     // > 0 for this geometry
            float r = __builtin_amdgcn_rcpf(U);
            float ts = fmaf(Xk, c, Yk * s);          // k1 * (X cos + Y sin)
            float v  = ts * r;                        // u - center
            float u  = v + hc;
            float fi = floorf(u);
            float w  = u - fi;
            int i0   = (int)fi;
            int i0c  = min(max(i0, 0), ndet - 1);
            int i1c  = min(i0c + 1, ndet - 1);       // exact: invalid region is zeroed
            float d  = dso_s * r;
            float wt = d * d;
            wt = (fabsf(v) <= hc) ? wt : 0.0f;       // single-compare validity
            float q00 = fb0[rowoff + i0c];
            float q01 = fb0[rowoff + i1c];
            float q10 = fb1[rowoff + i0c];
            float q11 = fb1[rowoff + i1c];
            acc0 = fmaf(fmaf(q01 - q00, w, q00), wt, acc0);
            acc1 = fmaf(fmaf(q11 - q10, w, q10), wt, acc1);
        }
        size_t px = (size_t)cy * 512 + cx;
        out[px]              = fmaf(sp0[3], acc0, sp0[4]);
        out[px + 512 * 512]  = fmaf(sp1[3], acc1, sp1[4]);
    } else {
        for (int b = 0; b < B; ++b) {
            const float* pb = ws + 736 + b * PB_SIZE;
            const float* sp = pb + S_OFF;
            __syncthreads();
            for (int i = tid; i < 2 * nang; i += 256)
                sc[i] = pb[i];
            __syncthreads();
            float dso_s = sp[0];
            float k1    = sp[1];
            float center= sp[2];
            float As    = sp[3];
            float Bs    = sp[4];
            const float* fb = filtered + (size_t)b * nang * ndet;
            float acc = 0.0f;
            float detm1 = (float)(ndet - 1);
            for (int a = 0; a < nang; ++a) {
                float s = sc[2 * a];
                float c = sc[2 * a + 1];
                float U = dso_s + X * s - Y * c;
                float r = __builtin_amdgcn_rcpf(U);
                float t = X * c + Y * s;
                float u = k1 * t * r + center;
                float fi = floorf(u);
                float w = u - fi;
                int i0 = (int)fi;
                int i0c = min(max(i0, 0), ndet - 1);
                int i1c = min(max(i0 + 1, 0), ndet - 1);
                const float* frow = fb + (size_t)a * ndet;
                float q0 = frow[i0c];
                float q1 = frow[i1c];
                float d = dso_s * r;
                float wt = d * d;
                bool valid = (u >= 0.0f) && (u <= detm1);
                float val = q0 + (q1 - q0) * w;
                acc += valid ? val * wt : 0.0f;
            }
            out[((size_t)b * 512 + cy) * 512 + cx] = As * acc + Bs;
        }
    }
}

extern "C" void kernel_launch(void* const* d_in, const int* in_sizes, int n_in,
                              void* d_out, int out_size, void* d_ws, size_t ws_size,
                              hipStream_t stream)
{
    const float* sino   = (const float*)d_in[0];
    const float* angles = (const float*)d_in[1];
    const float* dso    = (const float*)d_in[2];
    const float* ddo    = (const float*)d_in[3];
    const float* du     = (const float*)d_in[4];
    const float* hu     = (const float*)d_in[5];
    float* ws  = (float*)d_ws;
    float* out = (float*)d_out;

    int B    = in_sizes[2];
    int nang = in_sizes[1] / B;
    int ndet = in_sizes[0] / (B * nang);

    float* filtered = ws + 736 + B * PB_SIZE;

    prep_kernel<<<B, 256, 0, stream>>>(angles, dso, ddo, du, hu, ws, nang, ndet, B);
    filter_kernel<<<dim3(nang, B), 256, 0, stream>>>(sino, ws, filtered, nang, ndet);
    backproject_fused<<<dim3(512 / 16, 512 / 16), dim3(16, 16), 0, stream>>>(
        ws, filtered, out, nang, ndet, B);
}